// Round 13
// baseline (640.104 us; speedup 1.0000x reference)
//
#include <hip/hip_runtime.h>

#define B_ 4
#define N_ 8192
#define C_ 16

// agg0m geometry (MFMA layer-1)
#define JT0 128
#define NT0 (N_ / JT0)   // 64 tiles
#define CLB0 (JT0 + 8)   // 136 B code row stride (34 dwords, ≡2 mod 4)
#define HSH0 (JT0 + 4)   // 132 halves h row stride (66 dwords, ≡2 mod 4)

// aggm geometry (MFMA layers 2/3, round-11 verified)
#define JTC 256
#define NTC (N_ / JTC)   // 32 tiles
#define CLB (JTC + 8)    // 264 B
#define HSH (JTC + 4)    // 260 halves

// fallback geometry
#define JT 512
#define NT (N_ / JT)
#define LSTR (JT + 8)

typedef _Float16 f16;
typedef f16   f16x2 __attribute__((ext_vector_type(2)));
typedef f16   f16x4 __attribute__((ext_vector_type(4)));
typedef f16   f16x8 __attribute__((ext_vector_type(8)));
typedef float fv4   __attribute__((ext_vector_type(4)));
typedef float f32x4 __attribute__((ext_vector_type(4)));
typedef unsigned int ui2 __attribute__((ext_vector_type(2)));
typedef unsigned int ui4 __attribute__((ext_vector_type(4)));

union v8u { f16x8 v8; f16x2 v2[4]; unsigned int u[4]; };

// v_dot2_f32_f16: d = a.x*b.x + a.y*b.y + c (f32 accumulate, full-rate VALU)
__device__ __forceinline__ float fdot2(f16x2 a, f16x2 b, float c) {
    float d;
    asm("v_dot2_f32_f16 %0, %1, %2, %3" : "=v"(d) : "v"(a), "v"(b), "v"(c));
    return d;
}

// ---- 8-bit adjacency code (round-5 verified): code = (f16_bits + 32) >> 6
__device__ __forceinline__ unsigned int enc1(float f) {
    f16 h = (f16)f;
    unsigned short us = __builtin_bit_cast(unsigned short, h);
    return ((unsigned int)us + 32u) >> 6;   // <= 240
}
__device__ __forceinline__ void dec4(unsigned int d, f16x2& p01, f16x2& p23) {
#if __has_builtin(__builtin_amdgcn_perm)
    unsigned int t0 = __builtin_amdgcn_perm(d, d, 0x0C010C00u) << 6;
    unsigned int t1 = __builtin_amdgcn_perm(d, d, 0x0C030C02u) << 6;
#else
    unsigned int t0 = ((d & 0xFFu) | ((d << 8) & 0x00FF0000u)) << 6;
    unsigned int t1 = (((d >> 16) & 0xFFu) | ((d >> 8) & 0x00FF0000u)) << 6;
#endif
    p01 = __builtin_bit_cast(f16x2, t0);
    p23 = __builtin_bit_cast(f16x2, t1);
}

// ============ proj_t: hT[b][c][n] = f16( bias[c] + sum_k in[b][n][k] * W[c][k] ) ============
__global__ __launch_bounds__(256) void proj_t_kernel(const float* __restrict__ hin,
                                                     const float* __restrict__ W,
                                                     const float* __restrict__ bias,
                                                     f16* __restrict__ hT) {
    __shared__ float Ws[C_ * C_];
    __shared__ float bs[C_];
    int t = threadIdx.x;
    Ws[t] = W[t];
    if (t < C_) bs[t] = bias[t];
    __syncthreads();
    int nn = blockIdx.x * 256 + t;
    int b = nn >> 13, n = nn & (N_ - 1);
    const fv4* hv = (const fv4*)(hin + (size_t)nn * C_);
    fv4 q0 = hv[0], q1 = hv[1], q2 = hv[2], q3 = hv[3];
    float hr[16] = {q0[0], q0[1], q0[2], q0[3], q1[0], q1[1], q1[2], q1[3],
                    q2[0], q2[1], q2[2], q2[3], q3[0], q3[1], q3[2], q3[3]};
    f16* dst = hT + ((size_t)b * C_) * N_ + n;
#pragma unroll
    for (int c = 0; c < 16; ++c) {
        float s = bs[c];
#pragma unroll
        for (int k = 0; k < 16; ++k) s += hr[k] * Ws[c * 16 + k];
        dst[(size_t)c * N_] = (f16)s;
    }
}

// ============ agg0m: layer-1 via MFMA. Read fp32 adj (nt, 1-tile prefetch), encode to
// 8-bit codes (LDS stage + NORMAL global store -> L3 resident), deg from decoded codes,
// MFMA aggregation from LDS, fused proj epilogue -> hTout.
// Block = 64 rows, 4 waves (wave w -> rows i0+w*16..+16); grid (N/64, B).
__global__ __launch_bounds__(256) void agg0m_kernel(const float* __restrict__ adjf,
                                                    unsigned char* __restrict__ adjc_out,
                                                    const f16* __restrict__ hTin,
                                                    float* __restrict__ deg,
                                                    const float* __restrict__ Wp,
                                                    const float* __restrict__ bp,
                                                    f16* __restrict__ hTout) {
    __shared__ unsigned char cl[2][64][CLB0];   // 17.4 KB codes
    __shared__ f16 hs[2][C_][HSH0];             // 8.4 KB h-tile
    __shared__ float accL[4][16][C_ + 1];       // 4.4 KB
    __shared__ float Ws[C_ * C_ + C_];
    __shared__ float dpart[64][5];
    __shared__ float degf[64];

    const int b = blockIdx.y;
    const int i0 = blockIdx.x * 64;
    const int t = threadIdx.x;
    const int wave = t >> 6, lane = t & 63;
    const int m = lane & 15, kg = lane >> 4;

    Ws[t] = Wp[t];
    if (t < C_) Ws[C_ * C_ + t] = bp[t];

    // staging geometry: codes 64 rows x 128 B (4 thr/row x 32 B); h 16 ch x 128 halves (8/thr)
    const int crow = t >> 2, cq = t & 3, coff = cq * 32;
    const int hrow = t >> 4, hoff = (t & 15) * 8;
    const float* abase = adjf + ((size_t)b * N_ + i0 + crow) * (size_t)N_;
    unsigned char* cobase = adjc_out + ((size_t)b * N_ + i0 + crow) * (size_t)N_;
    const f16* hbase = hTin + (size_t)b * C_ * N_ + (size_t)hrow * N_;

    fv4 areg[8];
    f16x8 hreg;
    auto ld_regs = [&](int jt) {
#pragma unroll
        for (int k = 0; k < 8; ++k)
            areg[k] = __builtin_nontemporal_load((const fv4*)(abase + jt + coff + k * 4));
        hreg = *(const f16x8*)(hbase + jt + hoff);
    };

    f32x4 acc = {0.f, 0.f, 0.f, 0.f};
    float dsum = 0.f;
    const f16x2 ones = {(f16)1.f, (f16)1.f};
    const int arow_l = wave * 16 + m;

    ld_regs(0);
    for (int tile = 0; tile < NT0; ++tile) {
        const int buf = tile & 1;
        // encode 32 values -> 8 dwords (bit-path identical to verified agg0)
        unsigned int cw[8];
#pragma unroll
        for (int k = 0; k < 8; ++k) {
            cw[k] = enc1(areg[k][0]) | (enc1(areg[k][1]) << 8) |
                    (enc1(areg[k][2]) << 16) | (enc1(areg[k][3]) << 24);
        }
        // LDS code stage (32 B)
#pragma unroll
        for (int k = 0; k < 4; ++k) {
            ui2 w; w.x = cw[2 * k]; w.y = cw[2 * k + 1];
            *(ui2*)&cl[buf][crow][coff + k * 8] = w;
        }
        // global code store (NORMAL -> L3-resident for aggm1/2)
        {
            ui4 s0 = {cw[0], cw[1], cw[2], cw[3]};
            ui4 s1 = {cw[4], cw[5], cw[6], cw[7]};
            *(ui4*)(cobase + tile * JT0 + coff) = s0;
            *(ui4*)(cobase + tile * JT0 + coff + 16) = s1;
        }
        // h-tile stage
        {
            union { f16x8 v; f16x4 q[2]; } hh; hh.v = hreg;
            *(f16x4*)&hs[buf][hrow][hoff] = hh.q[0];
            *(f16x4*)&hs[buf][hrow][hoff + 4] = hh.q[1];
        }
        // deg partial from DECODED codes (consistency -> bias cancellation)
#pragma unroll
        for (int k = 0; k < 8; ++k) {
            f16x2 p01, p23;
            dec4(cw[k], p01, p23);
            dsum = fdot2(p01, ones, dsum);
            dsum = fdot2(p23, ones, dsum);
        }
        if (tile + 1 < NT0) ld_regs((tile + 1) * JT0);
        __syncthreads();
        // MFMA over this tile (4 chunks of K=32)
#pragma unroll
        for (int ks = 0; ks < JT0 / 32; ++ks) {
            const int col = ks * 32 + kg * 8;
            ui2 cwv = *(const ui2*)&cl[buf][arow_l][col];
            v8u a;
            dec4(cwv.x, a.v2[0], a.v2[1]);
            dec4(cwv.y, a.v2[2], a.v2[3]);
            v8u bf;
            ui2 b0 = *(const ui2*)&hs[buf][m][col];
            ui2 b1 = *(const ui2*)&hs[buf][m][col + 4];
            bf.u[0] = b0.x; bf.u[1] = b0.y; bf.u[2] = b1.x; bf.u[3] = b1.y;
            acc = __builtin_amdgcn_mfma_f32_16x16x32_f16(a.v8, bf.v8, acc, 0, 0, 0);
        }
        // NOTE: one barrier/tile; same double-buffer race discipline as verified aggm.
    }

    // deg reduce (4 partials per row) + accumulator dump
    dpart[crow][cq] = dsum;
#pragma unroll
    for (int r = 0; r < 4; ++r) accL[wave][kg * 4 + r][m] = acc[r];
    __syncthreads();
    if (t < 64) {
        float d = dpart[t][0] + dpart[t][1] + dpart[t][2] + dpart[t][3];
        degf[t] = d;
        deg[(size_t)b * N_ + i0 + t] = d;
    }
    __syncthreads();

    // fused proj epilogue: 64 rows x 16 outputs
#pragma unroll
    for (int it = 0; it < 4; ++it) {
        const int idx = t + it * 256;
        const int row = idx >> 4, ec = idx & 15;
        const int w2 = row >> 4, rl = row & 15;
        const float dvv = degf[row];
        float p = Ws[C_ * C_ + ec];
#pragma unroll
        for (int c = 0; c < C_; ++c) {
            float o = accL[w2][rl][c] / dvv;
            o = o > 0.f ? o : 0.f;
            p += o * Ws[ec * C_ + c];
        }
        hTout[(size_t)b * C_ * N_ + (size_t)ec * N_ + (i0 + row)] = (f16)p;
    }
}

// ============ aggm: MFMA aggregation from LDS-staged codes (round-11/12 verified).
// Codes read with NORMAL loads (L3-resident). MODE 1: fused proj. MODE 2: g fp32.
template <int MODE>
__global__ __launch_bounds__(256) void aggm_kernel(const unsigned char* __restrict__ adjc,
                                                   const f16* __restrict__ hTin,
                                                   const float* __restrict__ deg,
                                                   const float* __restrict__ Wp,
                                                   const float* __restrict__ bp,
                                                   f16* __restrict__ hTout,
                                                   float* __restrict__ gout) {
    __shared__ unsigned char cl[2][64][CLB];     // 33.8 KB codes
    __shared__ f16 hs[2][C_][HSH];               // 16.6 KB h-tile
    __shared__ float accL[4][16][C_ + 1];        // 4.4 KB
    __shared__ float Ws[C_ * C_ + C_];

    const int b = blockIdx.y;
    const int i0 = blockIdx.x * 64;
    const int t = threadIdx.x;
    const int wave = t >> 6, lane = t & 63;
    const int m = lane & 15, kg = lane >> 4;

    if (MODE == 1) {
        Ws[t] = Wp[t];
        if (t < C_) Ws[C_ * C_ + t] = bp[t];
    }

    // staging geometry: codes 64 rows x 256 B (64 B/thread); h 16 ch x 256 halves (16/thread)
    const int crow = t >> 2, coff = (t & 3) * 64;
    const int hrow = t >> 4, hoff = (t & 15) * 16;
    const unsigned char* cbase = adjc + ((size_t)b * N_ + i0 + crow) * (size_t)N_;
    const f16* hbase = hTin + (size_t)b * C_ * N_ + (size_t)hrow * N_;

    fv4 creg[4];
    f16x8 hreg0, hreg1;
    auto ld_regs = [&](int jt) {
#pragma unroll
        for (int k = 0; k < 4; ++k)
            creg[k] = *(const fv4*)(cbase + jt + coff + k * 16);   // NORMAL: L3 hit
        hreg0 = *(const f16x8*)(hbase + jt + hoff);
        hreg1 = *(const f16x8*)(hbase + jt + hoff + 8);
    };
    auto st_lds = [&](int buf) {
#pragma unroll
        for (int k = 0; k < 4; ++k) {
            union { fv4 v; ui2 h[2]; } cc; cc.v = creg[k];
            *(ui2*)&cl[buf][crow][coff + k * 16] = cc.h[0];
            *(ui2*)&cl[buf][crow][coff + k * 16 + 8] = cc.h[1];
        }
        union { f16x8 v; f16x4 q[2]; } h0, h1;
        h0.v = hreg0; h1.v = hreg1;
        *(f16x4*)&hs[buf][hrow][hoff + 0]  = h0.q[0];
        *(f16x4*)&hs[buf][hrow][hoff + 4]  = h0.q[1];
        *(f16x4*)&hs[buf][hrow][hoff + 8]  = h1.q[0];
        *(f16x4*)&hs[buf][hrow][hoff + 12] = h1.q[1];
    };

    f32x4 acc = {0.f, 0.f, 0.f, 0.f};
    const int arow_l = wave * 16 + m;

    ld_regs(0);
    for (int tile = 0; tile < NTC; ++tile) {
        const int buf = tile & 1;
        st_lds(buf);
        if (tile + 1 < NTC) ld_regs((tile + 1) * JTC);
        __syncthreads();
#pragma unroll
        for (int ks = 0; ks < JTC / 32; ++ks) {   // 8 chunks of K=32
            const int col = ks * 32 + kg * 8;
            ui2 cw = *(const ui2*)&cl[buf][arow_l][col];
            v8u a;
            dec4(cw.x, a.v2[0], a.v2[1]);
            dec4(cw.y, a.v2[2], a.v2[3]);
            v8u bf;
            ui2 b0 = *(const ui2*)&hs[buf][m][col];
            ui2 b1 = *(const ui2*)&hs[buf][m][col + 4];
            bf.u[0] = b0.x; bf.u[1] = b0.y; bf.u[2] = b1.x; bf.u[3] = b1.y;
            acc = __builtin_amdgcn_mfma_f32_16x16x32_f16(a.v8, bf.v8, acc, 0, 0, 0);
        }
    }

    // D layout (round-2 verified): row = kg*4 + r, col(channel) = m
#pragma unroll
    for (int r = 0; r < 4; ++r)
        accL[wave][kg * 4 + r][m] = acc[r];
    __syncthreads();

    // epilogue: 64 rows x 16 outputs
#pragma unroll
    for (int it = 0; it < 4; ++it) {
        const int idx = t + it * 256;
        const int row = idx >> 4, ec = idx & 15;
        const int w2 = row >> 4, rl = row & 15;
        const float dvv = deg[(size_t)b * N_ + i0 + row];
        if (MODE == 1) {
            float p = Ws[C_ * C_ + ec];
#pragma unroll
            for (int c = 0; c < C_; ++c) {
                float o = accL[w2][rl][c] / dvv;
                o = o > 0.f ? o : 0.f;
                p += o * Ws[ec * C_ + c];
            }
            hTout[(size_t)b * C_ * N_ + (size_t)ec * N_ + (i0 + row)] = (f16)p;
        } else {
            float o = accL[w2][rl][ec] / dvv;
            gout[((size_t)b * N_ + i0 + row) * C_ + ec] = o > 0.f ? o : 0.f;
        }
    }
}

// ============ final: two-stage deterministic reduction ============
__global__ __launch_bounds__(256) void final_partial(const float* __restrict__ g,
                                                     const float* __restrict__ Wfl,
                                                     float* __restrict__ partial) {
    const int bx = blockIdx.x;                 // b*32 + o*16 + chunk
    const int b = bx >> 5, o = (bx >> 4) & 1, chunk = bx & 15;
    const size_t base = (size_t)chunk * 8192;
    const fv4* hv = (const fv4*)(g + (size_t)b * N_ * C_ + base);
    const fv4* wv = (const fv4*)(Wfl + (size_t)o * N_ * C_ + base);
    float s = 0.f;
#pragma unroll
    for (int k = 0; k < 8; ++k) {
        int idx = threadIdx.x + k * 256;
        fv4 a = hv[idx], w = wv[idx];
        s += a[0] * w[0] + a[1] * w[1] + a[2] * w[2] + a[3] * w[3];
    }
#pragma unroll
    for (int m = 32; m >= 1; m >>= 1) s += __shfl_xor(s, m, 64);
    __shared__ float wsum[4];
    if ((threadIdx.x & 63) == 0) wsum[threadIdx.x >> 6] = s;
    __syncthreads();
    if (threadIdx.x == 0) partial[bx] = wsum[0] + wsum[1] + wsum[2] + wsum[3];
}

__global__ void final_reduce(const float* __restrict__ partial,
                             const float* __restrict__ bfl,
                             float* __restrict__ out) {
    int i = threadIdx.x;
    if (i < B_ * 2) {
        float s = bfl[i & 1];
        for (int k = 0; k < 16; ++k) s += partial[i * 16 + k];
        out[i] = s;
    }
}

// ===================== fallback (round-1 fp32 path, known-passing) =====================
__global__ __launch_bounds__(256) void proj_kernel(const float* __restrict__ hin,
                                                   const float* __restrict__ W,
                                                   const float* __restrict__ bias,
                                                   float* __restrict__ hout,
                                                   int total_nodes) {
    __shared__ float Ws[C_ * C_];
    __shared__ float bs[C_];
    int t = threadIdx.x;
    if (t < C_ * C_) Ws[t] = W[t];
    if (t < C_) bs[t] = bias[t];
    __syncthreads();
    int n = blockIdx.x * 256 + t;
    if (n >= total_nodes) return;
    const fv4* hv = (const fv4*)(hin + (size_t)n * C_);
    fv4 q0 = hv[0], q1 = hv[1], q2 = hv[2], q3 = hv[3];
    float hr[16] = {q0[0], q0[1], q0[2], q0[3], q1[0], q1[1], q1[2], q1[3],
                    q2[0], q2[1], q2[2], q2[3], q3[0], q3[1], q3[2], q3[3]};
    float o[16];
#pragma unroll
    for (int c = 0; c < 16; ++c) {
        float s = bs[c];
#pragma unroll
        for (int k = 0; k < 16; ++k) s += hr[k] * Ws[c * 16 + k];
        o[c] = s;
    }
    fv4* ov = (fv4*)(hout + (size_t)n * C_);
    ov[0] = fv4{o[0], o[1], o[2], o[3]};
    ov[1] = fv4{o[4], o[5], o[6], o[7]};
    ov[2] = fv4{o[8], o[9], o[10], o[11]};
    ov[3] = fv4{o[12], o[13], o[14], o[15]};
}

__global__ __launch_bounds__(256) void agg_kernel_f32(const float* __restrict__ adj,
                                                      const float* __restrict__ hin,
                                                      float* __restrict__ hout) {
    __shared__ fv4 hsf[JT][5];
    const int b = blockIdx.y;
    const int i0 = blockIdx.x * 16;
    const int t = threadIdx.x;
    const int wave = t >> 6;
    const int lane = t & 63;
    const int r0 = i0 + wave * 4;
    const float* adjb = adj + (size_t)b * N_ * N_;
    const float* hb = hin + (size_t)b * N_ * C_;
    const float* ar[4];
#pragma unroll
    for (int r = 0; r < 4; ++r) ar[r] = adjb + (size_t)(r0 + r) * N_;
    float acc[4][16];
#pragma unroll
    for (int r = 0; r < 4; ++r)
#pragma unroll
        for (int c = 0; c < 16; ++c) acc[r][c] = 0.f;
    float rs[4] = {0.f, 0.f, 0.f, 0.f};
    for (int jt = 0; jt < N_; jt += JT) {
        const fv4* src = (const fv4*)(hb + (size_t)jt * C_);
#pragma unroll
        for (int k = 0; k < (JT * C_ / 4) / 256; ++k) {
            int g = t + k * 256;
            hsf[g >> 2][g & 3] = src[g];
        }
        __syncthreads();
#pragma unroll 2
        for (int jj = lane; jj < JT; jj += 64) {
            fv4 q0 = hsf[jj][0], q1 = hsf[jj][1], q2 = hsf[jj][2], q3 = hsf[jj][3];
            float hv[16] = {q0[0], q0[1], q0[2], q0[3], q1[0], q1[1], q1[2], q1[3],
                            q2[0], q2[1], q2[2], q2[3], q3[0], q3[1], q3[2], q3[3]};
#pragma unroll
            for (int r = 0; r < 4; ++r) {
                float av = ar[r][jt + jj];
                rs[r] += av;
#pragma unroll
                for (int c = 0; c < 16; ++c) acc[r][c] += av * hv[c];
            }
        }
        __syncthreads();
    }
#pragma unroll
    for (int r = 0; r < 4; ++r) {
#pragma unroll
        for (int c = 0; c < 16; ++c) {
            float v = acc[r][c];
            for (int mm = 32; mm >= 1; mm >>= 1) v += __shfl_xor(v, mm, 64);
            acc[r][c] = v;
        }
        float d = rs[r];
        for (int mm = 32; mm >= 1; mm >>= 1) d += __shfl_xor(d, mm, 64);
        rs[r] = d;
    }
    if (lane == 0) {
#pragma unroll
        for (int r = 0; r < 4; ++r) {
            float inv = 1.0f / rs[r];
            fv4* dst = (fv4*)(hout + (size_t)b * N_ * C_ + (size_t)(r0 + r) * C_);
#pragma unroll
            for (int q = 0; q < 4; ++q) {
                fv4 ov;
#pragma unroll
                for (int e = 0; e < 4; ++e) {
                    float v = acc[r][q * 4 + e] * inv;
                    ov[e] = v > 0.f ? v : 0.f;
                }
                dst[q] = ov;
            }
        }
    }
}

// ========================================================================================
extern "C" void kernel_launch(void* const* d_in, const int* in_sizes, int n_in,
                              void* d_out, int out_size, void* d_ws, size_t ws_size,
                              hipStream_t stream) {
    const float* x   = (const float*)d_in[0];
    const float* adj = (const float*)d_in[1];
    const float* Wp  = (const float*)d_in[2];
    const float* bp  = (const float*)d_in[3];
    const float* Wfl = (const float*)d_in[4];
    const float* bfl = (const float*)d_in[5];
    float* out = (float*)d_out;

    const size_t adjc_b = (size_t)B_ * N_ * N_;                 // 256 MB (8-bit codes)
    const size_t deg_b  = (size_t)B_ * N_ * sizeof(float);      // 128 KB
    const size_t hT_b   = (size_t)B_ * C_ * N_ * sizeof(f16);   // 1 MB
    const size_t g_b    = (size_t)B_ * N_ * C_ * sizeof(float); // 2 MB
    const size_t part_b = 128 * sizeof(float);

    if (ws_size >= adjc_b + deg_b + 2 * hT_b + g_b + part_b) {
        char* p = (char*)d_ws;
        unsigned char* adjc = (unsigned char*)p; p += adjc_b;
        float* deg     = (float*)p; p += deg_b;
        f16* hTa       = (f16*)p;   p += hT_b;
        f16* hTb       = (f16*)p;   p += hT_b;
        float* g       = (float*)p; p += g_b;
        float* partial = (float*)p;

        const int pblocks = B_ * N_ / 256;
        dim3 agm(N_ / 64, B_);

        proj_t_kernel<<<pblocks, 256, 0, stream>>>(x, Wp, bp, hTa);
        agg0m_kernel<<<agm, 256, 0, stream>>>(adj, adjc, hTa, deg, Wp, bp, hTb);
        aggm_kernel<1><<<agm, 256, 0, stream>>>(adjc, hTb, deg, Wp, bp, hTa, nullptr);
        aggm_kernel<2><<<agm, 256, 0, stream>>>(adjc, hTa, deg, Wp, bp, nullptr, g);
        final_partial<<<B_ * 32, 256, 0, stream>>>(g, Wfl, partial);
        final_reduce<<<1, 64, 0, stream>>>(partial, bfl, out);
    } else {
        float* hA = (float*)d_ws;
        float* hB = hA + (size_t)B_ * N_ * C_;
        float* partial = hB + (size_t)B_ * N_ * C_;
        const int nodes = B_ * N_;
        dim3 aggGrid(N_ / 16, B_);
        proj_kernel<<<(nodes + 255) / 256, 256, 0, stream>>>(x, Wp, bp, hA, nodes);
        agg_kernel_f32<<<aggGrid, 256, 0, stream>>>(adj, hA, hB);
        proj_kernel<<<(nodes + 255) / 256, 256, 0, stream>>>(hB, Wp, bp, hA, nodes);
        agg_kernel_f32<<<aggGrid, 256, 0, stream>>>(adj, hA, hB);
        proj_kernel<<<(nodes + 255) / 256, 256, 0, stream>>>(hB, Wp, bp, hA, nodes);
        agg_kernel_f32<<<aggGrid, 256, 0, stream>>>(adj, hA, hB);
        final_partial<<<B_ * 32, 256, 0, stream>>>(hB, Wfl, partial);
        final_reduce<<<1, 64, 0, stream>>>(partial, bfl, out);
    }
}

// Round 14
// 392.216 us; speedup vs baseline: 1.6320x; 1.6320x over previous
//
#include <hip/hip_runtime.h>

#define B_ 4
#define N_ 8192
#define C_ 16
#define JT 512
#define NT (N_ / JT)     // 16 tiles (agg0)
#define LSTR (JT + 8)    // agg0 h-tile row stride (halves)

// MFMA aggc geometry
#define JTC 256
#define NTC (N_ / JTC)   // 32 tiles
#define CLB (JTC + 8)    // codes row stride: 264 B = 66 dwords (≡2 mod 4 -> ≤4-way b64)
#define HSH (JTC + 4)    // h row stride: 260 halves = 130 dwords (≡2 mod 4)

typedef _Float16 f16;
typedef f16   f16x2 __attribute__((ext_vector_type(2)));
typedef f16   f16x4 __attribute__((ext_vector_type(4)));
typedef f16   f16x8 __attribute__((ext_vector_type(8)));
typedef float fv4   __attribute__((ext_vector_type(4)));
typedef float f32x4 __attribute__((ext_vector_type(4)));
typedef unsigned int ui2 __attribute__((ext_vector_type(2)));

union v8u { f16x8 v8; f16x2 v2[4]; unsigned int u[4]; };
union cvu { fv4 v; ui2 h[2]; };

// v_dot2_f32_f16: d = a.x*b.x + a.y*b.y + c (f32 accumulate, full-rate VALU)
__device__ __forceinline__ float fdot2(f16x2 a, f16x2 b, float c) {
    float d;
    asm("v_dot2_f32_f16 %0, %1, %2, %3" : "=v"(d) : "v"(a), "v"(b), "v"(c));
    return d;
}

#define DOT8(accv, au, hu)                          \
    do {                                            \
        accv = fdot2((au).v2[0], (hu).v2[0], accv); \
        accv = fdot2((au).v2[1], (hu).v2[1], accv); \
        accv = fdot2((au).v2[2], (hu).v2[2], accv); \
        accv = fdot2((au).v2[3], (hu).v2[3], accv); \
    } while (0)

// ---- 8-bit adjacency code (round-5 verified): code = (f16_bits + 32) >> 6
__device__ __forceinline__ unsigned int enc1(float f) {
    f16 h = (f16)f;
    unsigned short us = __builtin_bit_cast(unsigned short, h);
    return ((unsigned int)us + 32u) >> 6;   // <= 240
}
__device__ __forceinline__ void dec4(unsigned int d, f16x2& p01, f16x2& p23) {
#if __has_builtin(__builtin_amdgcn_perm)
    unsigned int t0 = __builtin_amdgcn_perm(d, d, 0x0C010C00u) << 6;
    unsigned int t1 = __builtin_amdgcn_perm(d, d, 0x0C030C02u) << 6;
#else
    unsigned int t0 = ((d & 0xFFu) | ((d << 8) & 0x00FF0000u)) << 6;
    unsigned int t1 = (((d >> 16) & 0xFFu) | ((d >> 8) & 0x00FF0000u)) << 6;
#endif
    p01 = __builtin_bit_cast(f16x2, t0);
    p23 = __builtin_bit_cast(f16x2, t1);
}
__device__ __forceinline__ void dec8(ui2 d, v8u& out) {
    dec4(d.x, out.v2[0], out.v2[1]);
    dec4(d.y, out.v2[2], out.v2[3]);
}

// ============ proj_t: hT[b][c][n] = f16( bias[c] + sum_k in[b][n][k] * W[c][k] ) ============
__global__ __launch_bounds__(256) void proj_t_kernel(const float* __restrict__ hin,
                                                     const float* __restrict__ W,
                                                     const float* __restrict__ bias,
                                                     f16* __restrict__ hT) {
    __shared__ float Ws[C_ * C_];
    __shared__ float bs[C_];
    int t = threadIdx.x;
    Ws[t] = W[t];
    if (t < C_) bs[t] = bias[t];
    __syncthreads();
    int nn = blockIdx.x * 256 + t;
    int b = nn >> 13, n = nn & (N_ - 1);
    const fv4* hv = (const fv4*)(hin + (size_t)nn * C_);
    fv4 q0 = hv[0], q1 = hv[1], q2 = hv[2], q3 = hv[3];
    float hr[16] = {q0[0], q0[1], q0[2], q0[3], q1[0], q1[1], q1[2], q1[3],
                    q2[0], q2[1], q2[2], q2[3], q3[0], q3[1], q3[2], q3[3]};
    f16* dst = hT + ((size_t)b * C_) * N_ + n;
#pragma unroll
    for (int c = 0; c < 16; ++c) {
        float s = bs[c];
#pragma unroll
        for (int k = 0; k < 16; ++k) s += hr[k] * Ws[c * 16 + k];
        dst[(size_t)c * N_] = (f16)s;
    }
}

// ============ agg0: read fp32 adj (nt, prefetched — nt protects L3 for the codes),
// write 8-bit codes (NORMAL stores -> stay L2/L3 resident) + deg, fused proj -> hTout.
// 4 waves x 4 rows; grid (N/16, B).  [round-12 verified: coalesced 2KB-span row reads]
__global__ __launch_bounds__(256) void agg0_kernel(const float* __restrict__ adjf,
                                                   unsigned char* __restrict__ adjc_out,
                                                   const f16* __restrict__ hTin,
                                                   float* __restrict__ deg,
                                                   const float* __restrict__ Wp,
                                                   const float* __restrict__ bp,
                                                   f16* __restrict__ hTout) {
    __shared__ f16 hs[2][C_][LSTR];
    __shared__ float Ws[C_ * C_ + C_];
    __shared__ float accL[4][4][C_ + 1];

    const int b = blockIdx.y;
    const int i0 = blockIdx.x * 16;
    const int t = threadIdx.x;
    const int wave = t >> 6, lane = t & 63;
    const int r0 = i0 + wave * 4;

    Ws[t] = Wp[t];
    if (t < C_) Ws[C_ * C_ + t] = bp[t];

    const f16* hTb = hTin + (size_t)b * C_ * N_;
    const int srow = t >> 4, schunk = t & 15;
    auto stage = [&](int buf, int jt) {
        const f16* src = hTb + (size_t)srow * N_ + jt + schunk * 8;
#pragma unroll
        for (int k = 0; k < 4; ++k) {
            f16x8 v = *(const f16x8*)(src + k * 128);
            *(f16x8*)&hs[buf][srow][schunk * 8 + k * 128] = v;
        }
    };

    size_t arow[4];
#pragma unroll
    for (int r = 0; r < 4; ++r) arow[r] = ((size_t)b * N_ + (r0 + r)) * (size_t)N_;

    float acc[4][C_];
#pragma unroll
    for (int r = 0; r < 4; ++r)
#pragma unroll
        for (int c = 0; c < C_; ++c) acc[r][c] = 0.f;
    float ds4[4] = {0.f, 0.f, 0.f, 0.f};
    const f16x2 ones = {(f16)1.f, (f16)1.f};

    fv4 pf0[4], pf1[4];
    auto load_adj = [&](int jb) {
#pragma unroll
        for (int r = 0; r < 4; ++r) {
            pf0[r] = __builtin_nontemporal_load((const fv4*)(adjf + arow[r] + jb));
            pf1[r] = __builtin_nontemporal_load((const fv4*)(adjf + arow[r] + jb) + 1);
        }
    };

    load_adj(lane * 8);
    stage(0, 0);

    for (int tile = 0; tile < NT; ++tile) {
        __syncthreads();
        if (tile + 1 < NT) stage((tile + 1) & 1, (tile + 1) * JT);
        const int buf = tile & 1;
        const int jb = tile * JT + lane * 8;

        fv4 c0[4], c1[4];
#pragma unroll
        for (int r = 0; r < 4; ++r) { c0[r] = pf0[r]; c1[r] = pf1[r]; }
        if (tile + 1 < NT) load_adj((tile + 1) * JT + lane * 8);

        v8u av[4];
#pragma unroll
        for (int r = 0; r < 4; ++r) {
            ui2 pk;
            pk.x = enc1(c0[r][0]) | (enc1(c0[r][1]) << 8) |
                   (enc1(c0[r][2]) << 16) | (enc1(c0[r][3]) << 24);
            pk.y = enc1(c1[r][0]) | (enc1(c1[r][1]) << 8) |
                   (enc1(c1[r][2]) << 16) | (enc1(c1[r][3]) << 24);
            *(ui2*)(adjc_out + arow[r] + jb) = pk;   // NORMAL store: L3-resident
            dec8(pk, av[r]);                         // decoded values -> deg consistent
        }
        v8u on; on.v2[0] = ones; on.v2[1] = ones; on.v2[2] = ones; on.v2[3] = ones;
#pragma unroll
        for (int r = 0; r < 4; ++r) DOT8(ds4[r], av[r], on);

#pragma unroll
        for (int c = 0; c < C_; ++c) {
            v8u hu;
            hu.v8 = *(const f16x8*)&hs[buf][c][lane * 8];
            DOT8(acc[0][c], av[0], hu);
            DOT8(acc[1][c], av[1], hu);
            DOT8(acc[2][c], av[2], hu);
            DOT8(acc[3][c], av[3], hu);
        }
    }

    float dv[4];
#pragma unroll
    for (int r = 0; r < 4; ++r)
#pragma unroll
        for (int c = 0; c < C_; ++c) {
            float v = acc[r][c];
#pragma unroll
            for (int m = 32; m >= 1; m >>= 1) v += __shfl_xor(v, m, 64);
            acc[r][c] = v;
        }
#pragma unroll
    for (int r = 0; r < 4; ++r) {
        float v = ds4[r];
#pragma unroll
        for (int m = 32; m >= 1; m >>= 1) v += __shfl_xor(v, m, 64);
        dv[r] = v;
    }
    if (lane == 0) {
#pragma unroll
        for (int r = 0; r < 4; ++r) deg[(size_t)b * N_ + r0 + r] = dv[r];
#pragma unroll
        for (int r = 0; r < 4; ++r)
#pragma unroll
            for (int c = 0; c < C_; ++c) accL[wave][r][c] = acc[r][c];
    }
    __syncthreads();

    if (lane < C_) {
        const int ec = lane;
#pragma unroll
        for (int r = 0; r < 4; ++r) {
            float p = Ws[C_ * C_ + ec];
#pragma unroll
            for (int c = 0; c < C_; ++c) {
                float o = accL[wave][r][c] / dv[r];
                o = o > 0.f ? o : 0.f;
                p += o * Ws[ec * C_ + c];
            }
            hTout[(size_t)b * C_ * N_ + (size_t)ec * N_ + (r0 + r)] = (f16)p;
        }
    }
}

// ============ aggm: MFMA aggregation from LDS-staged codes (round-11/12 verified).
// Codes read with NORMAL loads (L3-resident after agg0's normal stores).
// MODE 1: fused proj -> hTout.  MODE 2: write g fp32.
template <int MODE>
__global__ __launch_bounds__(256) void aggm_kernel(const unsigned char* __restrict__ adjc,
                                                   const f16* __restrict__ hTin,
                                                   const float* __restrict__ deg,
                                                   const float* __restrict__ Wp,
                                                   const float* __restrict__ bp,
                                                   f16* __restrict__ hTout,
                                                   float* __restrict__ gout) {
    __shared__ unsigned char cl[2][64][CLB];     // 33.8 KB codes
    __shared__ f16 hs[2][C_][HSH];               // 16.6 KB h-tile
    __shared__ float accL[4][16][C_ + 1];        // 4.4 KB
    __shared__ float Ws[C_ * C_ + C_];

    const int b = blockIdx.y;
    const int i0 = blockIdx.x * 64;
    const int t = threadIdx.x;
    const int wave = t >> 6, lane = t & 63;
    const int m = lane & 15, kg = lane >> 4;

    if (MODE == 1) {
        Ws[t] = Wp[t];
        if (t < C_) Ws[C_ * C_ + t] = bp[t];
    }

    // staging geometry: codes 64 rows x 256 B (64 B/thread); h 16 ch x 256 halves (16/thread)
    const int crow = t >> 2, coff = (t & 3) * 64;
    const int hrow = t >> 4, hoff = (t & 15) * 16;
    const unsigned char* cbase = adjc + ((size_t)b * N_ + i0 + crow) * (size_t)N_;
    const f16* hbase = hTin + (size_t)b * C_ * N_ + (size_t)hrow * N_;

    fv4 creg[4];
    f16x8 hreg0, hreg1;
    auto ld_regs = [&](int jt) {
#pragma unroll
        for (int k = 0; k < 4; ++k)
            creg[k] = *(const fv4*)(cbase + jt + coff + k * 16);   // NORMAL: L3 hit
        hreg0 = *(const f16x8*)(hbase + jt + hoff);
        hreg1 = *(const f16x8*)(hbase + jt + hoff + 8);
    };
    auto st_lds = [&](int buf) {
#pragma unroll
        for (int k = 0; k < 4; ++k) {
            cvu cc; cc.v = creg[k];
            *(ui2*)&cl[buf][crow][coff + k * 16] = cc.h[0];
            *(ui2*)&cl[buf][crow][coff + k * 16 + 8] = cc.h[1];
        }
        union { f16x8 v; f16x4 q[2]; } h0, h1;
        h0.v = hreg0; h1.v = hreg1;
        *(f16x4*)&hs[buf][hrow][hoff + 0]  = h0.q[0];
        *(f16x4*)&hs[buf][hrow][hoff + 4]  = h0.q[1];
        *(f16x4*)&hs[buf][hrow][hoff + 8]  = h1.q[0];
        *(f16x4*)&hs[buf][hrow][hoff + 12] = h1.q[1];
    };

    f32x4 acc = {0.f, 0.f, 0.f, 0.f};
    const int arow_l = wave * 16 + m;   // A row within block's 64

    ld_regs(0);
    for (int tile = 0; tile < NTC; ++tile) {
        const int buf = tile & 1;
        st_lds(buf);
        if (tile + 1 < NTC) ld_regs((tile + 1) * JTC);  // overlap next loads w/ compute
        __syncthreads();
#pragma unroll
        for (int ks = 0; ks < JTC / 32; ++ks) {   // 8 chunks of K=32
            const int col = ks * 32 + kg * 8;
            ui2 cw = *(const ui2*)&cl[buf][arow_l][col];
            v8u a;
            dec4(cw.x, a.v2[0], a.v2[1]);
            dec4(cw.y, a.v2[2], a.v2[3]);
            v8u bf;
            ui2 b0 = *(const ui2*)&hs[buf][m][col];
            ui2 b1 = *(const ui2*)&hs[buf][m][col + 4];
            bf.u[0] = b0.x; bf.u[1] = b0.y; bf.u[2] = b1.x; bf.u[3] = b1.y;
            acc = __builtin_amdgcn_mfma_f32_16x16x32_f16(a.v8, bf.v8, acc, 0, 0, 0);
        }
    }

    // D layout (round-2 verified): row = kg*4 + r, col(channel) = m
#pragma unroll
    for (int r = 0; r < 4; ++r)
        accL[wave][kg * 4 + r][m] = acc[r];
    __syncthreads();

    // epilogue: 64 rows x 16 outputs = 1024 items over 256 threads
#pragma unroll
    for (int it = 0; it < 4; ++it) {
        const int idx = t + it * 256;
        const int row = idx >> 4, ec = idx & 15;
        const int w2 = row >> 4, rl = row & 15;
        const float dvv = deg[(size_t)b * N_ + i0 + row];
        if (MODE == 1) {
            float p = Ws[C_ * C_ + ec];
#pragma unroll
            for (int c = 0; c < C_; ++c) {
                float o = accL[w2][rl][c] / dvv;
                o = o > 0.f ? o : 0.f;
                p += o * Ws[ec * C_ + c];
            }
            hTout[(size_t)b * C_ * N_ + (size_t)ec * N_ + (i0 + row)] = (f16)p;
        } else {
            float o = accL[w2][rl][ec] / dvv;
            gout[((size_t)b * N_ + i0 + row) * C_ + ec] = o > 0.f ? o : 0.f;
        }
    }
}

// ============ final: two-stage deterministic reduction ============
__global__ __launch_bounds__(256) void final_partial(const float* __restrict__ g,
                                                     const float* __restrict__ Wfl,
                                                     float* __restrict__ partial) {
    const int bx = blockIdx.x;                 // b*32 + o*16 + chunk
    const int b = bx >> 5, o = (bx >> 4) & 1, chunk = bx & 15;
    const size_t base = (size_t)chunk * 8192;
    const fv4* hv = (const fv4*)(g + (size_t)b * N_ * C_ + base);
    const fv4* wv = (const fv4*)(Wfl + (size_t)o * N_ * C_ + base);
    float s = 0.f;
#pragma unroll
    for (int k = 0; k < 8; ++k) {
        int idx = threadIdx.x + k * 256;
        fv4 a = hv[idx], w = wv[idx];
        s += a[0] * w[0] + a[1] * w[1] + a[2] * w[2] + a[3] * w[3];
    }
#pragma unroll
    for (int m = 32; m >= 1; m >>= 1) s += __shfl_xor(s, m, 64);
    __shared__ float wsum[4];
    if ((threadIdx.x & 63) == 0) wsum[threadIdx.x >> 6] = s;
    __syncthreads();
    if (threadIdx.x == 0) partial[bx] = wsum[0] + wsum[1] + wsum[2] + wsum[3];
}

__global__ void final_reduce(const float* __restrict__ partial,
                             const float* __restrict__ bfl,
                             float* __restrict__ out) {
    int i = threadIdx.x;
    if (i < B_ * 2) {
        float s = bfl[i & 1];
        for (int k = 0; k < 16; ++k) s += partial[i * 16 + k];
        out[i] = s;
    }
}

// ===================== fallback (round-1 fp32 path, known-passing) =====================
__global__ __launch_bounds__(256) void proj_kernel(const float* __restrict__ hin,
                                                   const float* __restrict__ W,
                                                   const float* __restrict__ bias,
                                                   float* __restrict__ hout,
                                                   int total_nodes) {
    __shared__ float Ws[C_ * C_];
    __shared__ float bs[C_];
    int t = threadIdx.x;
    if (t < C_ * C_) Ws[t] = W[t];
    if (t < C_) bs[t] = bias[t];
    __syncthreads();
    int n = blockIdx.x * 256 + t;
    if (n >= total_nodes) return;
    const fv4* hv = (const fv4*)(hin + (size_t)n * C_);
    fv4 q0 = hv[0], q1 = hv[1], q2 = hv[2], q3 = hv[3];
    float hr[16] = {q0[0], q0[1], q0[2], q0[3], q1[0], q1[1], q1[2], q1[3],
                    q2[0], q2[1], q2[2], q2[3], q3[0], q3[1], q3[2], q3[3]};
    float o[16];
#pragma unroll
    for (int c = 0; c < 16; ++c) {
        float s = bs[c];
#pragma unroll
        for (int k = 0; k < 16; ++k) s += hr[k] * Ws[c * 16 + k];
        o[c] = s;
    }
    fv4* ov = (fv4*)(hout + (size_t)n * C_);
    ov[0] = fv4{o[0], o[1], o[2], o[3]};
    ov[1] = fv4{o[4], o[5], o[6], o[7]};
    ov[2] = fv4{o[8], o[9], o[10], o[11]};
    ov[3] = fv4{o[12], o[13], o[14], o[15]};
}

__global__ __launch_bounds__(256) void agg_kernel_f32(const float* __restrict__ adj,
                                                      const float* __restrict__ hin,
                                                      float* __restrict__ hout) {
    __shared__ fv4 hsf[JT][5];
    const int b = blockIdx.y;
    const int i0 = blockIdx.x * 16;
    const int t = threadIdx.x;
    const int wave = t >> 6;
    const int lane = t & 63;
    const int r0 = i0 + wave * 4;
    const float* adjb = adj + (size_t)b * N_ * N_;
    const float* hb = hin + (size_t)b * N_ * C_;
    const float* ar[4];
#pragma unroll
    for (int r = 0; r < 4; ++r) ar[r] = adjb + (size_t)(r0 + r) * N_;
    float acc[4][16];
#pragma unroll
    for (int r = 0; r < 4; ++r)
#pragma unroll
        for (int c = 0; c < 16; ++c) acc[r][c] = 0.f;
    float rs[4] = {0.f, 0.f, 0.f, 0.f};
    for (int jt = 0; jt < N_; jt += JT) {
        const fv4* src = (const fv4*)(hb + (size_t)jt * C_);
#pragma unroll
        for (int k = 0; k < (JT * C_ / 4) / 256; ++k) {
            int g = t + k * 256;
            hsf[g >> 2][g & 3] = src[g];
        }
        __syncthreads();
#pragma unroll 2
        for (int jj = lane; jj < JT; jj += 64) {
            fv4 q0 = hsf[jj][0], q1 = hsf[jj][1], q2 = hsf[jj][2], q3 = hsf[jj][3];
            float hv[16] = {q0[0], q0[1], q0[2], q0[3], q1[0], q1[1], q1[2], q1[3],
                            q2[0], q2[1], q2[2], q2[3], q3[0], q3[1], q3[2], q3[3]};
#pragma unroll
            for (int r = 0; r < 4; ++r) {
                float av = ar[r][jt + jj];
                rs[r] += av;
#pragma unroll
                for (int c = 0; c < 16; ++c) acc[r][c] += av * hv[c];
            }
        }
        __syncthreads();
    }
#pragma unroll
    for (int r = 0; r < 4; ++r) {
#pragma unroll
        for (int c = 0; c < 16; ++c) {
            float v = acc[r][c];
            for (int mm = 32; mm >= 1; mm >>= 1) v += __shfl_xor(v, mm, 64);
            acc[r][c] = v;
        }
        float d = rs[r];
        for (int mm = 32; mm >= 1; mm >>= 1) d += __shfl_xor(d, mm, 64);
        rs[r] = d;
    }
    if (lane == 0) {
#pragma unroll
        for (int r = 0; r < 4; ++r) {
            float inv = 1.0f / rs[r];
            fv4* dst = (fv4*)(hout + (size_t)b * N_ * C_ + (size_t)(r0 + r) * C_);
#pragma unroll
            for (int q = 0; q < 4; ++q) {
                fv4 ov;
#pragma unroll
                for (int e = 0; e < 4; ++e) {
                    float v = acc[r][q * 4 + e] * inv;
                    ov[e] = v > 0.f ? v : 0.f;
                }
                dst[q] = ov;
            }
        }
    }
}

// ========================================================================================
extern "C" void kernel_launch(void* const* d_in, const int* in_sizes, int n_in,
                              void* d_out, int out_size, void* d_ws, size_t ws_size,
                              hipStream_t stream) {
    const float* x   = (const float*)d_in[0];
    const float* adj = (const float*)d_in[1];
    const float* Wp  = (const float*)d_in[2];
    const float* bp  = (const float*)d_in[3];
    const float* Wfl = (const float*)d_in[4];
    const float* bfl = (const float*)d_in[5];
    float* out = (float*)d_out;

    const size_t adjc_b = (size_t)B_ * N_ * N_;                 // 256 MB (8-bit codes)
    const size_t deg_b  = (size_t)B_ * N_ * sizeof(float);      // 128 KB
    const size_t hT_b   = (size_t)B_ * C_ * N_ * sizeof(f16);   // 1 MB
    const size_t g_b    = (size_t)B_ * N_ * C_ * sizeof(float); // 2 MB
    const size_t part_b = 128 * sizeof(float);

    if (ws_size >= adjc_b + deg_b + 2 * hT_b + g_b + part_b) {
        char* p = (char*)d_ws;
        unsigned char* adjc = (unsigned char*)p; p += adjc_b;
        float* deg     = (float*)p; p += deg_b;
        f16* hTa       = (f16*)p;   p += hT_b;
        f16* hTb       = (f16*)p;   p += hT_b;
        float* g       = (float*)p; p += g_b;
        float* partial = (float*)p;

        const int pblocks = B_ * N_ / 256;
        dim3 ag0(N_ / 16, B_);
        dim3 agm(N_ / 64, B_);

        proj_t_kernel<<<pblocks, 256, 0, stream>>>(x, Wp, bp, hTa);
        agg0_kernel<<<ag0, 256, 0, stream>>>(adj, adjc, hTa, deg, Wp, bp, hTb);
        aggm_kernel<1><<<agm, 256, 0, stream>>>(adjc, hTb, deg, Wp, bp, hTa, nullptr);
        aggm_kernel<2><<<agm, 256, 0, stream>>>(adjc, hTa, deg, Wp, bp, nullptr, g);
        final_partial<<<B_ * 32, 256, 0, stream>>>(g, Wfl, partial);
        final_reduce<<<1, 64, 0, stream>>>(partial, bfl, out);
    } else {
        float* hA = (float*)d_ws;
        float* hB = hA + (size_t)B_ * N_ * C_;
        float* partial = hB + (size_t)B_ * N_ * C_;
        const int nodes = B_ * N_;
        dim3 aggGrid(N_ / 16, B_);
        proj_kernel<<<(nodes + 255) / 256, 256, 0, stream>>>(x, Wp, bp, hA, nodes);
        agg_kernel_f32<<<aggGrid, 256, 0, stream>>>(adj, hA, hB);
        proj_kernel<<<(nodes + 255) / 256, 256, 0, stream>>>(hB, Wp, bp, hA, nodes);
        agg_kernel_f32<<<aggGrid, 256, 0, stream>>>(adj, hA, hB);
        proj_kernel<<<(nodes + 255) / 256, 256, 0, stream>>>(hB, Wp, bp, hA, nodes);
        agg_kernel_f32<<<aggGrid, 256, 0, stream>>>(adj, hA, hB);
        final_partial<<<B_ * 32, 256, 0, stream>>>(hB, Wfl, partial);
        final_reduce<<<1, 64, 0, stream>>>(partial, bfl, out);
    }
}